// Round 6
// baseline (348.305 us; speedup 1.0000x reference)
//
#include <hip/hip_runtime.h>
#include <cstddef>

// CAM module, algebraically restructured:
//   X = concat(rgb,hsv,lab) : [B=4, 192, N=65536] (f32)
//   G[b] = X X^T (192x192), s[b] = row sums        (K1, fp16 MFMA)
//   energy = (Wq G Wk^T + bq sk^T + sq bk^T + N bq bk^T)/8 ; att = softmax_d
//   M = att Wv (emitted as swizzled fp16) ; c0 = att bv   (K2, f32)
//   out = M X + c0                                  (K3, fp16 MFMA, memory-bound)
//
// Occupancy model (m69): waves/SIMD quantum steps at VGPR {64,128,256}.
// A 768-thr (12-wave) block needs 3 waves/SIMD; 2 blocks need 6 -> impossible
// for VGPR in (64,128]. So K1 uses 512-thr (8-wave) blocks: 2 blocks/CU = 4
// waves/SIMD, available at VGPR <= 128. Each block computes HALF the tile grid
// (acc[3][3]/wave); twin halves are dispatch-adjacent for L2 reuse of X.

#define NPIX 65536

typedef _Float16 half4_t __attribute__((ext_vector_type(4)));
typedef _Float16 half8_t __attribute__((ext_vector_type(8)));
typedef float f32x4_t __attribute__((ext_vector_type(4)));

// ---------------- K0: zero a float range ----------------
__global__ void k0_zero(float* __restrict__ p, int n) {
  int i = blockIdx.x * 256 + threadIdx.x;
  if (i < n) p[i] = 0.0f;
}

// ---------------- K1: Gram + row sums ----------------
// grid (256, 4): blockIdx.x = {bx[0..127], half}; 512 cols/block, 8 chunks of 64.
// Block = 8 waves (2x4): wave tile = 3x3 16x16 tiles of the half's 6x12 grid.
// LDS: 2 x [192][64] fp16 (XOR swizzle), 1 barrier/chunk; 1-deep reg prefetch.
// mode: 2 = direct partials (128 slots/batch), 1 = atomic partials (64, zeroed),
// 0 = atomicAdd into zeroed G.
__global__ __launch_bounds__(512, 4) void k1_gram(
    const float* __restrict__ rgb, const float* __restrict__ hsv, const float* __restrict__ lab,
    float* __restrict__ G, float* __restrict__ S, float* __restrict__ part, int mode) {
  __shared__ alignas(16) _Float16 lds2[2][12288];
  float* slds = (float*)&lds2[0][0];

  const int t = threadIdx.x;
  const int lane = t & 63;
  const int w = t >> 6;          // 0..7
  const int wi = w >> 2;         // 0..1: tile-row group (3 tiles = 48 rows of the half)
  const int wj = w & 3;          // 0..3: tile-col group (3 tiles = 48 cols)
  const int half = blockIdx.x & 1;
  const int bx = blockIdx.x >> 1;    // 0..127
  const int b = blockIdx.y;
  const int n0 = bx * 512;

  // staging: sub-step s in {0,1,2} covers rows s*64..s*64+63 (source s).
  // thread -> row rr = t>>3 within source, 8 cols at k8 = (t&7)*8.
  const int rr = t >> 3;         // 0..63
  const int k8 = (t & 7) * 8;    // 0..56
  const float* base[3] = {
      rgb + (size_t)(b * 64 + rr) * NPIX + n0 + k8,
      hsv + (size_t)(b * 64 + rr) * NPIX + n0 + k8,
      lab + (size_t)(b * 64 + rr) * NPIX + n0 + k8};

  f32x4_t acc[3][3];
  const f32x4_t zero4 = {0.0f, 0.0f, 0.0f, 0.0f};
#pragma unroll
  for (int a = 0; a < 3; ++a)
#pragma unroll
    for (int j = 0; j < 3; ++j) acc[a][j] = zero4;
  float s_acc[3] = {0.f, 0.f, 0.f};

  float4 P[6];
  auto loadC = [&](int cc) {
#pragma unroll
    for (int s = 0; s < 3; ++s) {
      P[2 * s] = *(const float4*)(base[s] + cc * 64);
      P[2 * s + 1] = *(const float4*)(base[s] + cc * 64 + 4);
    }
  };
  const int sw = (rr & 7) << 3;  // row&7 == rr&7 for all sub-steps (row = s*64+rr)
  auto writeL = [&](_Float16* buf) {
#pragma unroll
    for (int s = 0; s < 3; ++s) {
      float4 p0 = P[2 * s], p1 = P[2 * s + 1];
      s_acc[s] += (p0.x + p0.y + p0.z + p0.w) + (p1.x + p1.y + p1.z + p1.w);
      half8_t h;
      h[0] = (_Float16)p0.x; h[1] = (_Float16)p0.y; h[2] = (_Float16)p0.z; h[3] = (_Float16)p0.w;
      h[4] = (_Float16)p1.x; h[5] = (_Float16)p1.y; h[6] = (_Float16)p1.z; h[7] = (_Float16)p1.w;
      *(half8_t*)(buf + (s * 64 + rr) * 64 + (k8 ^ sw)) = h;
    }
  };
  auto compute = [&](const _Float16* buf) {
#pragma unroll
    for (int ks = 0; ks < 2; ++ks) {
      const int kc = ks * 32 + 8 * (lane >> 4);
      half8_t fA[3], fB[3];
#pragma unroll
      for (int a = 0; a < 3; ++a) {
        int rA = half * 96 + wi * 48 + a * 16 + (lane & 15);
        fA[a] = *(const half8_t*)(buf + rA * 64 + (kc ^ ((rA & 7) << 3)));
      }
#pragma unroll
      for (int j = 0; j < 3; ++j) {
        int rB = wj * 48 + j * 16 + (lane & 15);
        fB[j] = *(const half8_t*)(buf + rB * 64 + (kc ^ ((rB & 7) << 3)));
      }
#pragma unroll
      for (int a = 0; a < 3; ++a)
#pragma unroll
        for (int j = 0; j < 3; ++j)
          acc[a][j] = __builtin_amdgcn_mfma_f32_16x16x32_f16(fA[a], fB[j], acc[a][j], 0, 0, 0);
    }
  };

  loadC(0);
  for (int cc = 0; cc < 8; ++cc) {
    writeL(&lds2[cc & 1][0]);       // implicit vmcnt wait on P
    __syncthreads();                // 1 barrier/chunk (dbuf)
    if (cc + 1 < 8) loadC(cc + 1);  // issue after barrier
    compute(&lds2[cc & 1][0]);
  }

  // ---- flush Gram (this half's 54 tiles) ----
  if (mode == 2) {
    float* pb = part + (size_t)(b * 128 + bx) * 37056;
#pragma unroll
    for (int a = 0; a < 3; ++a)
#pragma unroll
      for (int j = 0; j < 3; ++j) {
        int tt = (half * 6 + wi * 3 + a) * 12 + (wj * 3 + j);
        *(f32x4_t*)(pb + tt * 256 + lane * 4) = acc[a][j];
      }
  } else if (mode == 1) {
    float* pb = part + (size_t)(b * 64 + (bx >> 1)) * 37056;
#pragma unroll
    for (int a = 0; a < 3; ++a)
#pragma unroll
      for (int j = 0; j < 3; ++j) {
        int tt = (half * 6 + wi * 3 + a) * 12 + (wj * 3 + j);
#pragma unroll
        for (int r = 0; r < 4; ++r)
          atomicAdd(pb + tt * 256 + lane * 4 + r, acc[a][j][r]);
      }
  } else {
    float* Gb = G + b * 36864;
#pragma unroll
    for (int a = 0; a < 3; ++a)
#pragma unroll
      for (int j = 0; j < 3; ++j) {
#pragma unroll
        for (int r = 0; r < 4; ++r) {
          int gr = (half * 6 + wi * 3 + a) * 16 + ((lane >> 4) << 2) + r;
          int gc = (wj * 3 + j) * 16 + (lane & 15);
          atomicAdd(Gb + gr * 192 + gc, acc[a][j][r]);
        }
      }
  }

  // ---- row sums (half 0 only; reuse lds2[0] front as f32 scratch) ----
  // last read of lds2[0] finished before the cc=7 barrier; cc=7 compute reads lds2[1].
  if (half == 0) {
#pragma unroll
    for (int s = 0; s < 3; ++s) slds[(s * 64 + rr) * 8 + (t & 7)] = s_acc[s];
    __syncthreads();
    if (t < 192) {
      float v = 0.f;
#pragma unroll
      for (int q = 0; q < 8; ++q) v += slds[t * 8 + q];
      if (mode == 2)
        part[(size_t)(b * 128 + bx) * 37056 + 36864 + t] = v;
      else if (mode == 1)
        atomicAdd(part + (size_t)(b * 64 + (bx >> 1)) * 37056 + 36864 + t, v);
      else
        atomicAdd(S + b * 192 + t, v);
    }
  }
}

// ---------------- K1.5: deterministic reduce of P partials/batch ----------------
__global__ void k1r_reduce(const float* __restrict__ part, float* __restrict__ G,
                           float* __restrict__ S, int P) {
  int idx = blockIdx.x * 256 + threadIdx.x;
  if (idx >= 4 * 37056) return;
  int b = idx / 37056;
  int flat = idx % 37056;
  const float* base = part + (size_t)b * P * 37056 + flat;
  float v0 = 0.f, v1 = 0.f, v2 = 0.f, v3 = 0.f;
  for (int q = 0; q < P; q += 4) {
    v0 += base[(size_t)(q + 0) * 37056];
    v1 += base[(size_t)(q + 1) * 37056];
    v2 += base[(size_t)(q + 2) * 37056];
    v3 += base[(size_t)(q + 3) * 37056];
  }
  float v = (v0 + v1) + (v2 + v3);
  if (flat < 36864) {
    int tt = flat >> 8;
    int I = tt / 12, J = tt % 12;
    int r = flat & 255;
    int lane = r >> 2, rg = r & 3;
    int row = I * 16 + ((lane >> 4) << 2) + rg;
    int col = J * 16 + (lane & 15);
    G[b * 36864 + row * 192 + col] = v;
  } else {
    S[b * 192 + (flat - 36864)] = v;
  }
}

// ---------------- K2: energy -> softmax -> M(fp16 swizzled), c0 ----------------
__global__ __launch_bounds__(256) void k2_small(
    const float* __restrict__ G, const float* __restrict__ S,
    const float* __restrict__ Wq, const float* __restrict__ bq,
    const float* __restrict__ Wk, const float* __restrict__ bk,
    const float* __restrict__ Wv, const float* __restrict__ bv,
    _Float16* __restrict__ Mh, float* __restrict__ c0w) {
  const int b = blockIdx.y;
  const int cbase = blockIdx.x * 8;
  const int t = threadIdx.x;
  __shared__ float T1[192 * 9];
  __shared__ float el[64 * 8];
  __shared__ float sq[8];
  __shared__ float sk[64];
  const float* Gb = G + b * 36864;
  const float* Sb = S + b * 192;

  if (t < 8) {
    float a = 0.f;
    const float* wq = Wq + (cbase + t) * 192;
    for (int i = 0; i < 192; ++i) a = fmaf(wq[i], Sb[i], a);
    sq[t] = a;
  } else if (t < 72) {
    int d = t - 8;
    float a = 0.f;
    const float* wk = Wk + d * 192;
    for (int j = 0; j < 192; ++j) a = fmaf(wk[j], Sb[j], a);
    sk[d] = a;
  }
  for (int e = t; e < 1536; e += 256) {
    int j = e % 192, cp = e / 192;
    const float* wq = Wq + (cbase + cp) * 192;
    float a = 0.f;
    for (int i = 0; i < 192; ++i) a = fmaf(wq[i], Gb[i * 192 + j], a);
    T1[j * 9 + cp] = a;
  }
  __syncthreads();
  for (int e = t; e < 512; e += 256) {
    int cp = e & 7, d = e >> 3;
    const float* wk = Wk + d * 192;
    float a = 0.f;
    for (int j = 0; j < 192; ++j) a = fmaf(T1[j * 9 + cp], wk[j], a);
    float bqc = bq[cbase + cp], bkd = bk[d];
    a += bqc * sk[d] + bkd * sq[cp] + 65536.0f * bqc * bkd;
    el[d * 8 + cp] = a * 0.125f;
  }
  __syncthreads();
  if (t < 8) {
    float mx = -3.0e38f;
    for (int d = 0; d < 64; ++d) mx = fmaxf(mx, el[d * 8 + t]);
    float sum = 0.f;
    for (int d = 0; d < 64; ++d) {
      float pv = expf(el[d * 8 + t] - mx);
      el[d * 8 + t] = pv;
      sum += pv;
    }
    float inv = 1.0f / sum;
    for (int d = 0; d < 64; ++d) el[d * 8 + t] *= inv;
  }
  __syncthreads();
  // M rows in fp16, swizzled exactly as K3's lds_m image: idx = c*192 + (i ^ ((c&7)<<3))
  for (int e = t; e < 1536; e += 256) {
    int i = e % 192, cp = e / 192;
    int c = cbase + cp;
    float a = 0.f;
    for (int d = 0; d < 64; ++d) a = fmaf(el[d * 8 + cp], Wv[d * 192 + i], a);
    Mh[(size_t)b * 12288 + c * 192 + (i ^ ((c & 7) << 3))] = (_Float16)a;
  }
  if (t < 8) {
    float a = 0.f;
    for (int d = 0; d < 64; ++d) a = fmaf(el[d * 8 + t], bv[d], a);
    c0w[b * 64 + cbase + t] = a;
  }
}

// ---------------- K3: out = M X + c0 (fp16 MFMA) ----------------
// grid (256, 4), block 256 (4 waves). Block: C[64 x 256n]; wave w: n-span w*64.
// X chunk [32 i][256 n] staged transposed into lds_x[n][32] fp16, swizzle i^=(n&3)<<3.
// M staged once (linear copy of pre-swizzled fp16 image). acc[4][4] = 64 VGPR.
__global__ __launch_bounds__(256, 3) void k3_out(
    const float* __restrict__ rgb, const float* __restrict__ hsv, const float* __restrict__ lab,
    const _Float16* __restrict__ Mh, const float* __restrict__ c0w, float* __restrict__ out) {
  __shared__ alignas(16) _Float16 lds_m[12288];
  __shared__ alignas(16) _Float16 lds_x[8192];
  __shared__ float c0l[64];
  const int t = threadIdx.x;
  const int lane = t & 63;
  const int w = t >> 6;
  const int b = blockIdx.y;
  const int nblk = blockIdx.x * 256;

  {  // stage M (24576 B) as 16B copies + c0
    const float4* msrc = (const float4*)(Mh + (size_t)b * 12288);
    float4* mdst = (float4*)lds_m;
#pragma unroll
    for (int k = 0; k < 6; ++k) mdst[t + 256 * k] = msrc[t + 256 * k];
    if (t < 64) c0l[t] = c0w[b * 64 + t];
  }

  const int xi = t & 31;   // i within chunk
  const int ng = t >> 5;   // 0..7: n-group of 32
  const float* srcs[3] = {rgb, hsv, lab};

  f32x4_t acc[4][4];
  const f32x4_t zero4 = {0.0f, 0.0f, 0.0f, 0.0f};
#pragma unroll
  for (int i = 0; i < 4; ++i)
#pragma unroll
    for (int j = 0; j < 4; ++j) acc[i][j] = zero4;

  float4 xr[8];
  auto xload = [&](int kc) {
    int ig = kc * 32 + xi;
    const float* p = srcs[ig >> 6] + (size_t)(b * 64 + (ig & 63)) * NPIX + nblk + ng * 32;
#pragma unroll
    for (int f = 0; f < 8; ++f) xr[f] = *(const float4*)(p + f * 4);
  };
  auto xwrite = [&]() {
#pragma unroll
    for (int f = 0; f < 8; ++f) {
      int n = ng * 32 + f * 4;
      lds_x[(n + 0) * 32 + (xi ^ 0)]  = (_Float16)xr[f].x;
      lds_x[(n + 1) * 32 + (xi ^ 8)]  = (_Float16)xr[f].y;
      lds_x[(n + 2) * 32 + (xi ^ 16)] = (_Float16)xr[f].z;
      lds_x[(n + 3) * 32 + (xi ^ 24)] = (_Float16)xr[f].w;
    }
  };

  const int g = lane >> 4;     // 0..3
  const int l15 = lane & 15;

  xload(0);
  for (int kc = 0; kc < 6; ++kc) {
    xwrite();
    __syncthreads();
    if (kc + 1 < 6) xload(kc + 1);
    half8_t fx[4], fm[4];
#pragma unroll
    for (int nt = 0; nt < 4; ++nt) {
      int n = w * 64 + nt * 16 + l15;
      fx[nt] = *(const half8_t*)(lds_x + n * 32 + ((8 * g) ^ ((n & 3) << 3)));
    }
#pragma unroll
    for (int ct = 0; ct < 4; ++ct) {
      int c = ct * 16 + l15;
      fm[ct] = *(const half8_t*)(lds_m + c * 192 + ((kc * 32 + 8 * g) ^ ((c & 7) << 3)));
    }
#pragma unroll
    for (int nt = 0; nt < 4; ++nt)
#pragma unroll
      for (int ct = 0; ct < 4; ++ct)
        acc[nt][ct] = __builtin_amdgcn_mfma_f32_16x16x32_f16(fx[nt], fm[ct], acc[nt][ct], 0, 0, 0);
    __syncthreads();
  }

  // epilogue: C-row (n) = 4*g + r from first operand, C-col (c) = l15 from second
#pragma unroll
  for (int ct = 0; ct < 4; ++ct) {
    int c = ct * 16 + l15;
    float c0v = c0l[c];
#pragma unroll
    for (int nt = 0; nt < 4; ++nt) {
      int n = nblk + w * 64 + nt * 16 + 4 * g;
      float4 o;
      o.x = acc[nt][ct][0] + c0v;
      o.y = acc[nt][ct][1] + c0v;
      o.z = acc[nt][ct][2] + c0v;
      o.w = acc[nt][ct][3] + c0v;
      *(float4*)(out + (size_t)(b * 64 + c) * NPIX + n) = o;
    }
  }
}

extern "C" void kernel_launch(void* const* d_in, const int* in_sizes, int n_in,
                              void* d_out, int out_size, void* d_ws, size_t ws_size,
                              hipStream_t stream) {
  const float* rgb = (const float*)d_in[0];
  const float* hsv = (const float*)d_in[1];
  const float* lab = (const float*)d_in[2];
  const float* Wq = (const float*)d_in[3];
  const float* bq = (const float*)d_in[4];
  const float* Wk = (const float*)d_in[5];
  const float* bk = (const float*)d_in[6];
  const float* Wv = (const float*)d_in[7];
  const float* bv = (const float*)d_in[8];
  float* out = (float*)d_out;
  float* ws = (float*)d_ws;

  float* G = ws;                            // 147456 f32
  float* S = ws + 147456;                   // 768
  _Float16* Mh = (_Float16*)(ws + 148224);  // 49152 halves = 24576 f32 slots
  float* c0w = ws + 172800;                 // 256
  float* part = ws + 173056;                // up to 512*37056 f32
  const size_t need2 = (size_t)(173056 + 512 * 37056) * 4;  // 76.6 MB
  const size_t need1 = (size_t)(173056 + 256 * 37056) * 4;  // 38.6 MB
  const int mode = ws_size >= need2 ? 2 : (ws_size >= need1 ? 1 : 0);

  if (mode == 1)
    k0_zero<<<dim3(37056), dim3(256), 0, stream>>>(part, 256 * 37056);
  else if (mode == 0)
    k0_zero<<<dim3(579), dim3(256), 0, stream>>>(ws, 148224);  // zero G + S

  k1_gram<<<dim3(256, 4), dim3(512), 0, stream>>>(rgb, hsv, lab, G, S, part, mode);
  if (mode)
    k1r_reduce<<<dim3(579), dim3(256), 0, stream>>>(part, G, S, mode == 2 ? 128 : 64);
  k2_small<<<dim3(8, 4), dim3(256), 0, stream>>>(G, S, Wq, bq, Wk, bk, Wv, bv, Mh, c0w);
  k3_out<<<dim3(256, 4), dim3(256), 0, stream>>>(rgb, hsv, lab, Mh, c0w, out);
}

// Round 7
// 154.725 us; speedup vs baseline: 2.2511x; 2.2511x over previous
//
#include <hip/hip_runtime.h>
#include <cstddef>

// CAM module, algebraically restructured:
//   X = concat(rgb,hsv,lab) : [B=4, 192, N=65536] (f32)
//   G[b] = X X^T (192x192), s[b] = row sums        (K1, fp16 MFMA, gl_lds DMA staging)
//   energy = (Wq G Wk^T + bq sk^T + sq bk^T + N bq bk^T)/8 ; att = softmax_d
//   M = att Wv (emitted as swizzled fp16) ; c0 = att bv   (K2, f32)
//   out = M X + c0                                  (K3, fp16 MFMA, memory-bound)
//
// Round 4/6 lesson: __launch_bounds__ 2nd arg caused VGPR caps of 85 and 64 ->
// scratch spills (+390 MB traffic). Never pass it aggressively; omit it.
// Round 2/3/5 lesson: per-chunk time stuck at 5.9 us regardless of grid shape:
// burst-load -> vmcnt(0) -> compute leaves the memory pipe idle ~65% of the
// time. Fix (this round): global_load_lds DMA staging of RAW f32 (swizzle baked
// into per-lane SOURCE address, LDS dest linear - m173 pattern), double-buffered,
// counted waits + raw s_barrier so chunk c+1's transfer rides under compute(c).
// f32->f16 conversion happens in registers at fragment-build time.

#define NPIX 65536

typedef _Float16 half8_t __attribute__((ext_vector_type(8)));
typedef float f32x4_t __attribute__((ext_vector_type(4)));

// ---------------- K0: zero a float range ----------------
__global__ void k0_zero(float* __restrict__ p, int n) {
  int i = blockIdx.x * 256 + threadIdx.x;
  if (i < n) p[i] = 0.0f;
}

// ---------------- K1: Gram + row sums ----------------
// grid (64, 4) = 256 blocks (1/CU), block 768 (12 waves as 3 row-groups x 4 col-groups).
// 1024 cols/block, 32 chunks of 32 f32 cols. LDS: 2 x [192][32] f32 (24 KB each).
// Staging: per chunk each wave issues 2 global_load_lds dwordx4 rounds (1 KB each);
// lds[row][g] (16B granule) holds X[row][4*(g ^ (row&7))] -> conflict-free b128
// fragment reads at granule gk ^ (row&7).
// Wave (wi,wj) in 3x4: A-tiles wi*4+a (a<4), B-tiles wj*3+j (j<3); acc[4][3].
// mode: 1 = direct partials (64 slots/batch), 0 = atomicAdd into zeroed G/S.
__global__ __launch_bounds__(768) void k1_gram(
    const float* __restrict__ rgb, const float* __restrict__ hsv, const float* __restrict__ lab,
    float* __restrict__ G, float* __restrict__ S, float* __restrict__ part, int mode) {
  __shared__ alignas(16) float ldsb[2][6144];  // 2 x 24 KB

  const int t = threadIdx.x;
  const int lane = t & 63;
  const int w = t >> 6;            // 0..11
  const int wi = w >> 2;           // 0..2: A row-group (4 tiles = 64 rows)
  const int wj = w & 3;            // 0..3: B col-group (3 tiles = 48 rows)
  const int b = blockIdx.y;
  const int bx = blockIdx.x;       // 0..63
  const int n0 = bx * 1024;

  // ---- staging source addresses (2 rounds per chunk) ----
  // round r: wave stages LDS f32 [(w*2+r)*256, +256) = rows (w*2+r)*8 .. +7.
  // lane l -> row = (w*2+r)*8 + (l>>3), granule g = l&7;
  // source granule sg = g ^ (row&7)  (XOR swizzle baked into source address).
  const float* gsrc[2];
#pragma unroll
  for (int r = 0; r < 2; ++r) {
    int row = (w * 2 + r) * 8 + (lane >> 3);
    int rs = row >> 6;  // uniform per (w,r): 8-row groups never straddle 64
    const float* sp = (rs == 0) ? rgb : (rs == 1) ? hsv : lab;
    int sg = (lane & 7) ^ (row & 7);
    gsrc[r] = sp + (size_t)(b * 64 + (row & 63)) * NPIX + n0 + 4 * sg;
  }

  f32x4_t acc[4][3];
  const f32x4_t zero4 = {0.0f, 0.0f, 0.0f, 0.0f};
#pragma unroll
  for (int a = 0; a < 4; ++a)
#pragma unroll
    for (int j = 0; j < 3; ++j) acc[a][j] = zero4;

  float srow = 0.0f;                 // row-sum partial: row t>>2, quarter t&3
  const int sr_r = t >> 2;
  const int sr_q = t & 3;

  const int l15 = lane & 15;
  const int gk = 2 * (lane >> 4);    // fragment granule base (k = 8*(lane>>4) f32)

  auto stage = [&](int cc) {
    const int par = cc & 1;
#pragma unroll
    for (int r = 0; r < 2; ++r) {
      __builtin_amdgcn_global_load_lds(
          (const __attribute__((address_space(1))) void*)(gsrc[r] + cc * 32),
          (__attribute__((address_space(3))) void*)(&ldsb[par][(w * 2 + r) * 256]),
          16, 0, 0);
    }
  };

  auto compute = [&](int cc) {
    const int par = cc & 1;
    half8_t fB16[3];
#pragma unroll
    for (int j = 0; j < 3; ++j) {
      int rB = wj * 48 + j * 16 + l15;
      f32x4_t lo = *(const f32x4_t*)(&ldsb[par][rB * 32 + ((gk ^ (rB & 7)) << 2)]);
      f32x4_t hi = *(const f32x4_t*)(&ldsb[par][rB * 32 + (((gk + 1) ^ (rB & 7)) << 2)]);
      half8_t f;
      f[0] = (_Float16)lo[0]; f[1] = (_Float16)lo[1];
      f[2] = (_Float16)lo[2]; f[3] = (_Float16)lo[3];
      f[4] = (_Float16)hi[0]; f[5] = (_Float16)hi[1];
      f[6] = (_Float16)hi[2]; f[7] = (_Float16)hi[3];
      fB16[j] = f;
    }
#pragma unroll
    for (int a = 0; a < 4; ++a) {
      int rA = wi * 64 + a * 16 + l15;
      f32x4_t lo = *(const f32x4_t*)(&ldsb[par][rA * 32 + ((gk ^ (rA & 7)) << 2)]);
      f32x4_t hi = *(const f32x4_t*)(&ldsb[par][rA * 32 + (((gk + 1) ^ (rA & 7)) << 2)]);
      half8_t fa;
      fa[0] = (_Float16)lo[0]; fa[1] = (_Float16)lo[1];
      fa[2] = (_Float16)lo[2]; fa[3] = (_Float16)lo[3];
      fa[4] = (_Float16)hi[0]; fa[5] = (_Float16)hi[1];
      fa[6] = (_Float16)hi[2]; fa[7] = (_Float16)hi[3];
#pragma unroll
      for (int j = 0; j < 3; ++j)
        acc[a][j] = __builtin_amdgcn_mfma_f32_16x16x32_f16(fa, fB16[j], acc[a][j], 0, 0, 0);
    }
    // row sums: this thread's 8 f32 of (row sr_r, granules 2q, 2q+1)
    {
      f32x4_t s0 = *(const f32x4_t*)(&ldsb[par][sr_r * 32 + (((2 * sr_q) ^ (sr_r & 7)) << 2)]);
      f32x4_t s1 = *(const f32x4_t*)(&ldsb[par][sr_r * 32 + (((2 * sr_q + 1) ^ (sr_r & 7)) << 2)]);
      srow += (s0[0] + s0[1]) + (s0[2] + s0[3]) + (s1[0] + s1[1]) + (s1[2] + s1[3]);
    }
  };

  stage(0);
  asm volatile("s_waitcnt vmcnt(0) lgkmcnt(0)" ::: "memory");
  __builtin_amdgcn_s_barrier();
  for (int cc = 0; cc < 32; ++cc) {
    if (cc + 1 < 32) stage(cc + 1);   // DMA for next buffer, in flight under compute
    compute(cc);
    asm volatile("s_waitcnt vmcnt(0) lgkmcnt(0)" ::: "memory");
    __builtin_amdgcn_s_barrier();
  }

  // ---- flush Gram ----
  if (mode) {
    float* pb = part + (size_t)(b * 64 + bx) * 37056;
#pragma unroll
    for (int a = 0; a < 4; ++a)
#pragma unroll
      for (int j = 0; j < 3; ++j) {
        int tt = (wi * 4 + a) * 12 + (wj * 3 + j);
        *(f32x4_t*)(pb + tt * 256 + lane * 4) = acc[a][j];
      }
  } else {
    float* Gb = G + b * 36864;
#pragma unroll
    for (int a = 0; a < 4; ++a)
#pragma unroll
      for (int j = 0; j < 3; ++j) {
#pragma unroll
        for (int r = 0; r < 4; ++r) {
          int gr = (wi * 4 + a) * 16 + ((lane >> 4) << 2) + r;
          int gc = (wj * 3 + j) * 16 + (lane & 15);
          atomicAdd(Gb + gr * 192 + gc, acc[a][j][r]);
        }
      }
  }

  // ---- row sums: reduce 4 quarters per row via LDS (buf0 is free) ----
  float* slds = &ldsb[0][0];
  __syncthreads();
  slds[t] = srow;
  __syncthreads();
  if (t < 192) {
    float v = (slds[4 * t] + slds[4 * t + 1]) + (slds[4 * t + 2] + slds[4 * t + 3]);
    if (mode)
      part[(size_t)(b * 64 + bx) * 37056 + 36864 + t] = v;
    else
      atomicAdd(S + b * 192 + t, v);
  }
}

// ---------------- K1.5: deterministic reduce of P partials/batch ----------------
__global__ void k1r_reduce(const float* __restrict__ part, float* __restrict__ G,
                           float* __restrict__ S, int P) {
  int idx = blockIdx.x * 256 + threadIdx.x;
  if (idx >= 4 * 37056) return;
  int b = idx / 37056;
  int flat = idx % 37056;
  const float* base = part + (size_t)b * P * 37056 + flat;
  float v0 = 0.f, v1 = 0.f, v2 = 0.f, v3 = 0.f;
  for (int q = 0; q < P; q += 4) {
    v0 += base[(size_t)(q + 0) * 37056];
    v1 += base[(size_t)(q + 1) * 37056];
    v2 += base[(size_t)(q + 2) * 37056];
    v3 += base[(size_t)(q + 3) * 37056];
  }
  float v = (v0 + v1) + (v2 + v3);
  if (flat < 36864) {
    int tt = flat >> 8;
    int I = tt / 12, J = tt % 12;
    int r = flat & 255;
    int lane = r >> 2, rg = r & 3;
    int row = I * 16 + ((lane >> 4) << 2) + rg;
    int col = J * 16 + (lane & 15);
    G[b * 36864 + row * 192 + col] = v;
  } else {
    S[b * 192 + (flat - 36864)] = v;
  }
}

// ---------------- K2: energy -> softmax -> M(fp16 swizzled), c0 ----------------
__global__ __launch_bounds__(256) void k2_small(
    const float* __restrict__ G, const float* __restrict__ S,
    const float* __restrict__ Wq, const float* __restrict__ bq,
    const float* __restrict__ Wk, const float* __restrict__ bk,
    const float* __restrict__ Wv, const float* __restrict__ bv,
    _Float16* __restrict__ Mh, float* __restrict__ c0w) {
  const int b = blockIdx.y;
  const int cbase = blockIdx.x * 8;
  const int t = threadIdx.x;
  __shared__ float T1[192 * 9];
  __shared__ float el[64 * 8];
  __shared__ float sq[8];
  __shared__ float sk[64];
  const float* Gb = G + b * 36864;
  const float* Sb = S + b * 192;

  if (t < 8) {
    float a = 0.f;
    const float* wq = Wq + (cbase + t) * 192;
    for (int i = 0; i < 192; ++i) a = fmaf(wq[i], Sb[i], a);
    sq[t] = a;
  } else if (t < 72) {
    int d = t - 8;
    float a = 0.f;
    const float* wk = Wk + d * 192;
    for (int j = 0; j < 192; ++j) a = fmaf(wk[j], Sb[j], a);
    sk[d] = a;
  }
  for (int e = t; e < 1536; e += 256) {
    int j = e % 192, cp = e / 192;
    const float* wq = Wq + (cbase + cp) * 192;
    float a = 0.f;
    for (int i = 0; i < 192; ++i) a = fmaf(wq[i], Gb[i * 192 + j], a);
    T1[j * 9 + cp] = a;
  }
  __syncthreads();
  for (int e = t; e < 512; e += 256) {
    int cp = e & 7, d = e >> 3;
    const float* wk = Wk + d * 192;
    float a = 0.f;
    for (int j = 0; j < 192; ++j) a = fmaf(T1[j * 9 + cp], wk[j], a);
    float bqc = bq[cbase + cp], bkd = bk[d];
    a += bqc * sk[d] + bkd * sq[cp] + 65536.0f * bqc * bkd;
    el[d * 8 + cp] = a * 0.125f;
  }
  __syncthreads();
  if (t < 8) {
    float mx = -3.0e38f;
    for (int d = 0; d < 64; ++d) mx = fmaxf(mx, el[d * 8 + t]);
    float sum = 0.f;
    for (int d = 0; d < 64; ++d) {
      float pv = expf(el[d * 8 + t] - mx);
      el[d * 8 + t] = pv;
      sum += pv;
    }
    float inv = 1.0f / sum;
    for (int d = 0; d < 64; ++d) el[d * 8 + t] *= inv;
  }
  __syncthreads();
  // M rows in fp16, swizzled exactly as K3's lds_m image: idx = c*192 + (i ^ ((c&7)<<3))
  for (int e = t; e < 1536; e += 256) {
    int i = e % 192, cp = e / 192;
    int c = cbase + cp;
    float a = 0.f;
    for (int d = 0; d < 64; ++d) a = fmaf(el[d * 8 + cp], Wv[d * 192 + i], a);
    Mh[(size_t)b * 12288 + c * 192 + (i ^ ((c & 7) << 3))] = (_Float16)a;
  }
  if (t < 8) {
    float a = 0.f;
    for (int d = 0; d < 64; ++d) a = fmaf(el[d * 8 + t], bv[d], a);
    c0w[b * 64 + cbase + t] = a;
  }
}

// ---------------- K3: out = M X + c0 (fp16 MFMA) ----------------
// grid (256, 4), block 256 (4 waves). Block: C[64 x 256n]; wave w: n-span w*64.
// X chunk [32 i][256 n] staged transposed into lds_x[n][32] fp16, swizzle i^=(n&3)<<3.
// M staged once (linear copy of pre-swizzled fp16 image). acc[4][4] = 64 VGPR.
__global__ __launch_bounds__(256, 3) void k3_out(
    const float* __restrict__ rgb, const float* __restrict__ hsv, const float* __restrict__ lab,
    const _Float16* __restrict__ Mh, const float* __restrict__ c0w, float* __restrict__ out) {
  __shared__ alignas(16) _Float16 lds_m[12288];
  __shared__ alignas(16) _Float16 lds_x[8192];
  __shared__ float c0l[64];
  const int t = threadIdx.x;
  const int lane = t & 63;
  const int w = t >> 6;
  const int b = blockIdx.y;
  const int nblk = blockIdx.x * 256;

  {  // stage M (24576 B) as 16B copies + c0
    const float4* msrc = (const float4*)(Mh + (size_t)b * 12288);
    float4* mdst = (float4*)lds_m;
#pragma unroll
    for (int k = 0; k < 6; ++k) mdst[t + 256 * k] = msrc[t + 256 * k];
    if (t < 64) c0l[t] = c0w[b * 64 + t];
  }

  const int xi = t & 31;   // i within chunk
  const int ng = t >> 5;   // 0..7: n-group of 32
  const float* srcs[3] = {rgb, hsv, lab};

  f32x4_t acc[4][4];
  const f32x4_t zero4 = {0.0f, 0.0f, 0.0f, 0.0f};
#pragma unroll
  for (int i = 0; i < 4; ++i)
#pragma unroll
    for (int j = 0; j < 4; ++j) acc[i][j] = zero4;

  float4 xr[8];
  auto xload = [&](int kc) {
    int ig = kc * 32 + xi;
    const float* p = srcs[ig >> 6] + (size_t)(b * 64 + (ig & 63)) * NPIX + nblk + ng * 32;
#pragma unroll
    for (int f = 0; f < 8; ++f) xr[f] = *(const float4*)(p + f * 4);
  };
  auto xwrite = [&]() {
#pragma unroll
    for (int f = 0; f < 8; ++f) {
      int n = ng * 32 + f * 4;
      lds_x[(n + 0) * 32 + (xi ^ 0)]  = (_Float16)xr[f].x;
      lds_x[(n + 1) * 32 + (xi ^ 8)]  = (_Float16)xr[f].y;
      lds_x[(n + 2) * 32 + (xi ^ 16)] = (_Float16)xr[f].z;
      lds_x[(n + 3) * 32 + (xi ^ 24)] = (_Float16)xr[f].w;
    }
  };

  const int g = lane >> 4;     // 0..3
  const int l15 = lane & 15;

  xload(0);
  for (int kc = 0; kc < 6; ++kc) {
    xwrite();
    __syncthreads();
    if (kc + 1 < 6) xload(kc + 1);
    half8_t fx[4], fm[4];
#pragma unroll
    for (int nt = 0; nt < 4; ++nt) {
      int n = w * 64 + nt * 16 + l15;
      fx[nt] = *(const half8_t*)(lds_x + n * 32 + ((8 * g) ^ ((n & 3) << 3)));
    }
#pragma unroll
    for (int ct = 0; ct < 4; ++ct) {
      int c = ct * 16 + l15;
      fm[ct] = *(const half8_t*)(lds_m + c * 192 + ((kc * 32 + 8 * g) ^ ((c & 7) << 3)));
    }
#pragma unroll
    for (int nt = 0; nt < 4; ++nt)
#pragma unroll
      for (int ct = 0; ct < 4; ++ct)
        acc[nt][ct] = __builtin_amdgcn_mfma_f32_16x16x32_f16(fx[nt], fm[ct], acc[nt][ct], 0, 0, 0);
    __syncthreads();
  }

  // epilogue: C-row (n) = 4*g + r from first operand, C-col (c) = l15 from second
#pragma unroll
  for (int ct = 0; ct < 4; ++ct) {
    int c = ct * 16 + l15;
    float c0v = c0l[c];
#pragma unroll
    for (int nt = 0; nt < 4; ++nt) {
      int n = nblk + w * 64 + nt * 16 + 4 * g;
      float4 o;
      o.x = acc[nt][ct][0] + c0v;
      o.y = acc[nt][ct][1] + c0v;
      o.z = acc[nt][ct][2] + c0v;
      o.w = acc[nt][ct][3] + c0v;
      *(float4*)(out + (size_t)(b * 64 + c) * NPIX + n) = o;
    }
  }
}

extern "C" void kernel_launch(void* const* d_in, const int* in_sizes, int n_in,
                              void* d_out, int out_size, void* d_ws, size_t ws_size,
                              hipStream_t stream) {
  const float* rgb = (const float*)d_in[0];
  const float* hsv = (const float*)d_in[1];
  const float* lab = (const float*)d_in[2];
  const float* Wq = (const float*)d_in[3];
  const float* bq = (const float*)d_in[4];
  const float* Wk = (const float*)d_in[5];
  const float* bk = (const float*)d_in[6];
  const float* Wv = (const float*)d_in[7];
  const float* bv = (const float*)d_in[8];
  float* out = (float*)d_out;
  float* ws = (float*)d_ws;

  float* G = ws;                            // 147456 f32
  float* S = ws + 147456;                   // 768
  _Float16* Mh = (_Float16*)(ws + 148224);  // 49152 halves = 24576 f32 slots
  float* c0w = ws + 172800;                 // 256
  float* part = ws + 173056;                // 256*37056 f32 (64 slots x 4 batches)
  const size_t need1 = (size_t)(173056 + 256 * 37056) * 4;  // 38.6 MB
  const int mode = ws_size >= need1 ? 1 : 0;

  if (!mode)
    k0_zero<<<dim3(579), dim3(256), 0, stream>>>(ws, 148224);  // zero G + S

  k1_gram<<<dim3(64, 4), dim3(768), 0, stream>>>(rgb, hsv, lab, G, S, part, mode);
  if (mode)
    k1r_reduce<<<dim3(579), dim3(256), 0, stream>>>(part, G, S, 64);
  k2_small<<<dim3(8, 4), dim3(256), 0, stream>>>(G, S, Wq, bq, Wk, bk, Wv, bv, Mh, c0w);
  k3_out<<<dim3(256, 4), dim3(256), 0, stream>>>(rgb, hsv, lab, Mh, c0w, out);
}